// Round 3
// baseline (2661.652 us; speedup 1.0000x reference)
//
#include <hip/hip_runtime.h>
#include <stdint.h>

#define BB 32
#define TT 64
#define ID 300
#define HH 168
#define SS 512
#define VV 50257
#define G4 672     // 4*H
#define IC 468     // I + C
#define KP 192     // K padded for decode MFMA
#define NP 50304   // V padded to 128
#define NJ 8       // blocks per batch (cluster size)
#define RPB 21     // h rows per block
#define CPB 84     // gate cols per block
#define KK 336     // gate K dim (attn 168 + h 168)
#define WKP 88     // WgT col pad (84 -> 88)
#define EPAD 172   // ETs LDS row pad (168 -> 172)
#define SBLK 64    // s positions per block

typedef float f32x4 __attribute__((ext_vector_type(4)));
typedef short bf16x8 __attribute__((ext_vector_type(8)));

__device__ __forceinline__ float bf2f(unsigned short u) {
  union { unsigned int i; float f; } v; v.i = ((unsigned int)u) << 16; return v.f;
}
__device__ __forceinline__ unsigned short f2bf(float f) {
  union { float f; unsigned int u; } v; v.f = f;
  unsigned int r = v.u + 0x7fffu + ((v.u >> 16) & 1u);
  return (unsigned short)(r >> 16);
}
__device__ __forceinline__ float rcpf(float x) { return __builtin_amdgcn_rcpf(x); }

// ---------------- W_ih x-part transpose (for k_xproj) -----------------------
__global__ void k_tr(const float* __restrict__ Wih, float* __restrict__ WihxT) {
  int idx = blockIdx.x * 256 + threadIdx.x;
  if (idx < ID * G4) {
    int k = idx / G4, i = idx - k * G4;
    WihxT[idx] = Wih[(size_t)i * IC + k];
  }
}

// ---------------- seq_proj -> ETs[b][s][h] = bf16(exp(2P)); ctxb bf16 -------
__global__ void k_seqproj(const float* __restrict__ ctx, const float* __restrict__ Ws,
                          unsigned short* __restrict__ ETs, unsigned short* __restrict__ ctxb) {
  const int b = blockIdx.x;
  const int s0 = blockIdx.y * 16;
  const int tid = threadIdx.x;
  __shared__ float ctxL[16 * HH];
  for (int idx = tid; idx < 16 * HH; idx += 256) {
    float v = ctx[(size_t)(b * SS + s0) * HH + idx];
    ctxL[idx] = v;
    ctxb[(size_t)(b * SS + s0) * HH + idx] = f2bf(v);
  }
  __syncthreads();
  #pragma unroll
  for (int o = 0; o < 11; ++o) {
    int idx = o * 256 + tid;
    if (idx < 16 * HH) {
      int s = idx / HH, h = idx - s * HH;
      const float* cr = &ctxL[s * HH];
      float acc = 0.f;
      #pragma unroll 4
      for (int c = 0; c < HH; ++c) acc = fmaf(cr[c], Ws[c * HH + h], acc);
      ETs[(size_t)(b * SS + s0 + s) * HH + h] = f2bf(__expf(2.f * acc));
    }
  }
}

// ---------------- X_proj[b][t][i] = x@WihxT + b_ih + b_hh --------------------
__global__ void k_xproj(const float* __restrict__ x, const float* __restrict__ WihxT,
                        const float* __restrict__ bih, const float* __restrict__ bhh,
                        float* __restrict__ Xp) {
  const int t0 = blockIdx.x * 8;
  const int b = blockIdx.y;
  const int tid = threadIdx.x;
  __shared__ float xL[8 * ID];
  for (int idx = tid; idx < 8 * ID; idx += 256)
    xL[idx] = x[(size_t)(b * TT + t0) * ID + idx];
  __syncthreads();
  for (int i = tid; i < G4; i += 256) {
    float bias = bih[i] + bhh[i];
    float acc[8];
    #pragma unroll
    for (int tt = 0; tt < 8; ++tt) acc[tt] = bias;
    for (int k = 0; k < ID; ++k) {
      float w = WihxT[k * G4 + i];
      #pragma unroll
      for (int tt = 0; tt < 8; ++tt) acc[tt] += xL[tt * ID + k] * w;
    }
    #pragma unroll
    for (int tt = 0; tt < 8; ++tt)
      Xp[(size_t)(b * TT + t0 + tt) * G4 + i] = acc[tt];
  }
}

// ---------------- W_dec -> bf16, padded (NP x KP) ----------------------------
__global__ void k_wdec(const float* __restrict__ Wd, unsigned short* __restrict__ Wdb) {
  size_t idx = (size_t)blockIdx.x * 256 + threadIdx.x;
  int v = (int)(idx / KP), k = (int)(idx - (size_t)v * KP);
  float val = (v < VV && k < HH) ? Wd[(size_t)v * HH + k] : 0.f;
  Wdb[idx] = f2bf(val);
}

// ---------------- WgT [NJ][336][88] fp32, WxS [NJ][21][168] bf16, flags, pad -
__global__ void k_prep(const float* __restrict__ Wih, const float* __restrict__ Whh,
                       const float* __restrict__ attWx, float* __restrict__ WgT,
                       unsigned short* __restrict__ WxS, unsigned int* __restrict__ flags,
                       unsigned short* __restrict__ hall) {
  int idx = blockIdx.x * 256 + threadIdx.x;
  const int T1 = NJ * KK * WKP;            // 236544
  const int T2 = T1 + NJ * RPB * HH;       // +28224
  const int T3 = T2 + 2 * BB * NJ * 64;    // +32768
  const int T4 = T3 + BB * TT * (KP - HH); // +49152
  if (idx < T1) {
    int j = idx / (KK * WKP); int r = idx - j * KK * WKP;
    int k = r / WKP, col = r - k * WKP;
    float w = 0.f;
    if (col < CPB) {
      int gt = col / RPB, rr = col - gt * RPB;
      int gcol = gt * HH + j * RPB + rr;
      w = (k < HH) ? Wih[(size_t)gcol * IC + ID + k] : Whh[(size_t)gcol * HH + (k - HH)];
    }
    WgT[idx] = w;
  } else if (idx < T2) {
    int r = idx - T1;
    WxS[r] = f2bf(attWx[r]);   // [j][row][col] flat == rows j*21.. of attWx
  } else if (idx < T3) {
    flags[idx - T2] = 0u;
  } else if (idx < T4) {
    int r = idx - T3;
    int bt = r / (KP - HH), c = r - bt * (KP - HH);
    hall[(size_t)bt * KP + HH + c] = 0;
  }
}

// ---------------- recurrence: 8 blocks per batch, flag-sync ------------------
__global__ __launch_bounds__(512, 1) void k_recur(
    const int* __restrict__ lens, const float* __restrict__ attb,
    const float* __restrict__ attv, const float* __restrict__ WgT,
    const unsigned short* __restrict__ WxS, const unsigned short* __restrict__ ETs,
    const unsigned short* __restrict__ ctxb, const float* __restrict__ Xp,
    float* __restrict__ Hbuf, float* __restrict__ Pbuf, float* __restrict__ APbuf,
    unsigned int* __restrict__ flags, unsigned short* __restrict__ hall) {
  const int b = blockIdx.x & 31;
  const int j = blockIdx.x >> 5;
  const int tid = threadIdx.x;

  __shared__ float WgL[KK][WKP];            // 118272 B, transposed [k][col]
  __shared__ unsigned short EL[SBLK][EPAD]; // 22016 B
  __shared__ unsigned short WxL[RPB][HH];   // 7056 B
  __shared__ float scratch[512];
  __shared__ float redH[504], redC[504];
  __shared__ float gE[HH], hsh[HH], abL[HH], vL[HH], attn[HH];
  __shared__ float esh[SBLK], gatesL[CPB], hLoc[RPB], cLoc[RPB];
  __shared__ float denr_s, sumv_s, bsum_s;

  // ---- stage static data
  {
    const f32x4* src = (const f32x4*)(WgT + (size_t)j * KK * WKP);
    f32x4* dst = (f32x4*)WgL;
    for (int i = tid; i < KK * WKP / 4; i += 512) dst[i] = src[i];
  }
  for (int i = tid; i < SBLK * HH; i += 512) {
    int s = i / HH, h = i - s * HH;
    EL[s][h] = ETs[((size_t)b * SS + j * SBLK + s) * HH + h];
  }
  for (int i = tid; i < RPB * HH; i += 512)
    ((unsigned short*)WxL)[i] = WxS[(size_t)j * RPB * HH + i];
  if (tid < HH) { abL[tid] = attb[tid]; vL[tid] = attv[tid]; }
  if (tid < RPB) cLoc[tid] = 0.f;
  __syncthreads();
  if (tid == 0) {
    float s = 0.f;
    for (int h = 0; h < HH; ++h) s += vL[h];
    sumv_s = s;
  }
  const int len = lens[b];
  const int sbase = j * SBLK;
  unsigned int* fB = flags + (size_t)(b * NJ) * 64;
  unsigned int* fA = flags + (size_t)BB * NJ * 64 + (size_t)(b * NJ) * 64;
  __syncthreads();

  for (int t = 0; t < TT; ++t) {
    // ---- 1/2: sync on h (flagB) + build gE, hsh
    if (t > 0) {
      if (tid < NJ) {
        int g = 0;
        while (__hip_atomic_load(&fB[tid * 64], __ATOMIC_RELAXED,
                                 __HIP_MEMORY_SCOPE_AGENT) < (unsigned)t) {
          __builtin_amdgcn_s_sleep(2);
          if (++g > (1 << 27)) break;
        }
      }
      __builtin_amdgcn_fence(__ATOMIC_ACQUIRE, "agent");
      __syncthreads();
      if (tid < HH) {
        float a = abL[tid];
        #pragma unroll
        for (int jj = 0; jj < NJ; ++jj)
          a += __hip_atomic_load(&APbuf[((size_t)b * NJ + jj) * HH + tid],
                                 __ATOMIC_RELAXED, __HIP_MEMORY_SCOPE_AGENT);
        gE[tid] = __expf(2.f * a);
        hsh[tid] = __hip_atomic_load(&Hbuf[(size_t)b * HH + tid],
                                     __ATOMIC_RELAXED, __HIP_MEMORY_SCOPE_AGENT);
      }
    } else {
      if (tid < HH) { gE[tid] = __expf(2.f * abL[tid]); hsh[tid] = 0.f; }
    }
    __syncthreads();
    // ---- 3: B: e-partials over own s-range
    {
      int sl = tid & 63, hs = tid >> 6;
      const unsigned short* er = &EL[sl][hs * RPB];
      const int hb = hs * RPB;
      float ep = 0.f;
      #pragma unroll 7
      for (int i = 0; i < RPB; ++i)
        ep += vL[hb + i] * rcpf(fmaf(gE[hb + i], bf2f(er[i]), 1.f));
      scratch[hs * 64 + sl] = ep;
    }
    __syncthreads();
    if (tid < SBLK) {
      float tot = 0.f;
      #pragma unroll
      for (int hs = 0; hs < 8; ++hs) tot += scratch[hs * 64 + tid];
      float eh = (sbase + tid < len) ? __expf(sumv_s - 2.f * tot) : 0.f;
      esh[tid] = eh;
      float r = eh;
      #pragma unroll
      for (int off = 32; off; off >>= 1) r += __shfl_down(r, off);
      if (tid == 0) bsum_s = r;
    }
    __syncthreads();
    // ---- 4: C: weighted-context partials, post + flagA
    if (tid < 504) {
      int c = tid % HH, ch = tid / HH;
      const unsigned short* cb = ctxb + ((size_t)b * SS + sbase) * HH + c;
      float p = 0.f;
      for (int s = ch; s < SBLK; s += 3)
        p = fmaf(esh[s], bf2f(cb[(size_t)s * HH]), p);
      scratch[ch * HH + c] = p;
    }
    __syncthreads();
    if (tid < HH) {
      float p = scratch[tid] + scratch[HH + tid] + scratch[2 * HH + tid];
      __hip_atomic_store(&Pbuf[((size_t)b * NJ + j) * 176 + tid], p,
                         __ATOMIC_RELAXED, __HIP_MEMORY_SCOPE_AGENT);
    } else if (tid == HH) {
      __hip_atomic_store(&Pbuf[((size_t)b * NJ + j) * 176 + HH], bsum_s,
                         __ATOMIC_RELAXED, __HIP_MEMORY_SCOPE_AGENT);
    }
    __syncthreads();
    if (tid == 0) {
      __builtin_amdgcn_fence(__ATOMIC_RELEASE, "agent");
      __hip_atomic_store(&fA[j * 64], (unsigned)(t + 1),
                         __ATOMIC_RELAXED, __HIP_MEMORY_SCOPE_AGENT);
    }
    // ---- 5: D_h (overlaps flagA propagation): Wh @ h_{t-1}
    if (tid < 504) {
      int col = tid % CPB, kc = tid / CPB;
      int k0 = HH + kc * 28;
      float acc = 0.f;
      #pragma unroll 7
      for (int i = 0; i < 28; ++i)
        acc = fmaf(WgL[k0 + i][col], hsh[kc * 28 + i], acc);
      redH[kc * CPB + col] = acc;
    }
    // ---- 6: poll flagA
    if (tid < NJ) {
      int g = 0;
      while (__hip_atomic_load(&fA[tid * 64], __ATOMIC_RELAXED,
                               __HIP_MEMORY_SCOPE_AGENT) < (unsigned)(t + 1)) {
        __builtin_amdgcn_s_sleep(2);
        if (++g > (1 << 27)) break;
      }
    }
    __builtin_amdgcn_fence(__ATOMIC_ACQUIRE, "agent");
    __syncthreads();
    // ---- 7: reduce partials -> attn
    if (tid < HH + 1) {
      float s = 0.f;
      #pragma unroll
      for (int jj = 0; jj < NJ; ++jj)
        s += __hip_atomic_load(&Pbuf[((size_t)b * NJ + jj) * 176 + tid],
                               __ATOMIC_RELAXED, __HIP_MEMORY_SCOPE_AGENT);
      if (tid < HH) scratch[tid] = s;
      else denr_s = 1.f / s;
    }
    __syncthreads();
    if (tid < HH) attn[tid] = scratch[tid] * denr_s;
    __syncthreads();
    // ---- 8: D_c: Wc @ attn
    if (tid < 504) {
      int col = tid % CPB, kc = tid / CPB;
      int k0 = kc * 28;
      float acc = 0.f;
      #pragma unroll 7
      for (int i = 0; i < 28; ++i)
        acc = fmaf(WgL[k0 + i][col], attn[k0 + i], acc);
      redC[kc * CPB + col] = acc;
    }
    __syncthreads();
    // ---- 9: gates + LSTM update
    if (tid < CPB) {
      int gt = tid / RPB, rr = tid - gt * RPB;
      int gcol = gt * HH + j * RPB + rr;
      float g = Xp[((size_t)b * TT + t) * G4 + gcol];
      #pragma unroll
      for (int kc = 0; kc < 6; ++kc) g += redH[kc * CPB + tid] + redC[kc * CPB + tid];
      gatesL[tid] = g;
    }
    __syncthreads();
    if (tid < RPB) {
      float ig = gatesL[tid], fg = gatesL[RPB + tid];
      float gg = gatesL[2 * RPB + tid], og = gatesL[3 * RPB + tid];
      float si = rcpf(1.f + __expf(-ig));
      float sf = rcpf(1.f + __expf(-fg));
      float so = rcpf(1.f + __expf(-og));
      float tg = 1.f - 2.f * rcpf(1.f + __expf(2.f * gg));
      float cn = fmaf(sf, cLoc[tid], si * tg);
      float tc = 1.f - 2.f * rcpf(1.f + __expf(2.f * cn));
      float hn = so * tc;
      cLoc[tid] = cn; hLoc[tid] = hn;
      hall[((size_t)b * TT + t) * KP + j * RPB + tid] = f2bf(hn);
      __hip_atomic_store(&Hbuf[(size_t)b * HH + j * RPB + tid], hn,
                         __ATOMIC_RELAXED, __HIP_MEMORY_SCOPE_AGENT);
    }
    __syncthreads();
    // ---- 10: a_j = h_slice @ Wx_slice, post + flagB
    if (tid < 504) {
      int col = tid % HH, ch = tid / HH;
      float acc = 0.f;
      #pragma unroll
      for (int r = ch * 7; r < ch * 7 + 7; ++r)
        acc = fmaf(hLoc[r], bf2f(WxL[r][col]), acc);
      scratch[ch * HH + col] = acc;
    }
    __syncthreads();
    if (tid < HH) {
      float a = scratch[tid] + scratch[HH + tid] + scratch[2 * HH + tid];
      __hip_atomic_store(&APbuf[((size_t)b * NJ + j) * HH + tid], a,
                         __ATOMIC_RELAXED, __HIP_MEMORY_SCOPE_AGENT);
    }
    __syncthreads();
    if (tid == 0) {
      __builtin_amdgcn_fence(__ATOMIC_RELEASE, "agent");
      __hip_atomic_store(&fB[j * 64], (unsigned)(t + 1),
                         __ATOMIC_RELAXED, __HIP_MEMORY_SCOPE_AGENT);
    }
  }
}

// ---------------- decode GEMM: out = hall(2048xKP) @ Wdb(NPxKP)^T -----------
__global__ __launch_bounds__(256) void k_decode(const unsigned short* __restrict__ hallb,
                                                const unsigned short* __restrict__ wdb,
                                                float* __restrict__ out) {
  __shared__ __align__(16) unsigned short As[128 * 64];
  __shared__ __align__(16) unsigned short Bs[128 * 64];
  const int tid = threadIdx.x;
  const int n0 = blockIdx.x * 128, m0 = blockIdx.y * 128;
  const int lane = tid & 63, wid = tid >> 6;
  const int wm = wid >> 1, wn = wid & 1;
  const int lr = lane & 15, lk = lane >> 4;
  f32x4 acc[4][4];
  #pragma unroll
  for (int i = 0; i < 4; ++i)
    #pragma unroll
    for (int jj = 0; jj < 4; ++jj) acc[i][jj] = (f32x4)0.f;

  for (int k0 = 0; k0 < KP; k0 += 64) {
    if (k0) __syncthreads();
    #pragma unroll
    for (int i = 0; i < 4; ++i) {
      int flat = i * 256 + tid;
      int row = flat >> 3;
      int col = (flat & 7) * 8;
      uint4 va = *(const uint4*)(hallb + (size_t)(m0 + row) * KP + k0 + col);
      *(uint4*)&As[row * 64 + col] = va;
      uint4 vb = *(const uint4*)(wdb + (size_t)(n0 + row) * KP + k0 + col);
      *(uint4*)&Bs[row * 64 + col] = vb;
    }
    __syncthreads();
    #pragma unroll
    for (int kk = 0; kk < 64; kk += 32) {
      bf16x8 af[4], bfr[4];
      #pragma unroll
      for (int mi = 0; mi < 4; ++mi)
        af[mi] = *(const bf16x8*)&As[(wm * 64 + mi * 16 + lr) * 64 + kk + lk * 8];
      #pragma unroll
      for (int ni = 0; ni < 4; ++ni)
        bfr[ni] = *(const bf16x8*)&Bs[(wn * 64 + ni * 16 + lr) * 64 + kk + lk * 8];
      #pragma unroll
      for (int mi = 0; mi < 4; ++mi)
        #pragma unroll
        for (int ni = 0; ni < 4; ++ni)
          acc[mi][ni] = __builtin_amdgcn_mfma_f32_16x16x32_bf16(
              af[mi], bfr[ni], acc[mi][ni], 0, 0, 0);
    }
  }
  #pragma unroll
  for (int mi = 0; mi < 4; ++mi)
    #pragma unroll
    for (int ni = 0; ni < 4; ++ni) {
      int col = n0 + wn * 64 + ni * 16 + lr;
      if (col < VV) {
        #pragma unroll
        for (int r = 0; r < 4; ++r) {
          int row = m0 + wm * 64 + mi * 16 + lk * 4 + r;
          out[(size_t)row * VV + col] = acc[mi][ni][r];
        }
      }
    }
}

extern "C" void kernel_launch(void* const* d_in, const int* in_sizes, int n_in,
                              void* d_out, int out_size, void* d_ws, size_t ws_size,
                              hipStream_t stream) {
  (void)in_sizes; (void)n_in; (void)out_size; (void)ws_size;
  const float* x     = (const float*)d_in[0];
  const float* ctx   = (const float*)d_in[1];
  const int*   lens  = (const int*)d_in[2];
  const float* Wih   = (const float*)d_in[3];
  const float* Whh   = (const float*)d_in[4];
  const float* bih   = (const float*)d_in[5];
  const float* bhh   = (const float*)d_in[6];
  const float* attWx = (const float*)d_in[7];
  const float* attWs = (const float*)d_in[8];
  const float* attb  = (const float*)d_in[9];
  const float* attv  = (const float*)d_in[10];
  const float* Wdec  = (const float*)d_in[11];
  float* out = (float*)d_out;

  char* base = (char*)d_ws;
  size_t off = 0;
  auto alloc = [&](size_t bytes) -> void* {
    off = (off + 255) & ~(size_t)255;
    void* p = base + off;
    off += bytes;
    return p;
  };
  unsigned short* ETs  = (unsigned short*)alloc((size_t)BB * SS * HH * 2);
  unsigned short* ctxb = (unsigned short*)alloc((size_t)BB * SS * HH * 2);
  float*          Xp   = (float*)alloc((size_t)BB * TT * G4 * 4);
  float*          WihxT= (float*)alloc((size_t)ID * G4 * 4);
  unsigned short* hall = (unsigned short*)alloc((size_t)BB * TT * KP * 2);
  unsigned short* Wdb  = (unsigned short*)alloc((size_t)NP * KP * 2);
  float*          WgT  = (float*)alloc((size_t)NJ * KK * WKP * 4);
  unsigned short* WxS  = (unsigned short*)alloc((size_t)NJ * RPB * HH * 2);
  float*          Hbuf = (float*)alloc((size_t)BB * HH * 4);
  float*          Pbuf = (float*)alloc((size_t)BB * NJ * 176 * 4);
  float*          APbuf= (float*)alloc((size_t)BB * NJ * HH * 4);
  unsigned int*   flags= (unsigned int*)alloc((size_t)2 * BB * NJ * 64 * 4);

  k_tr<<<dim3((ID * G4 + 255) / 256), dim3(256), 0, stream>>>(Wih, WihxT);
  k_seqproj<<<dim3(BB, SS / 16), dim3(256), 0, stream>>>(ctx, attWs, ETs, ctxb);
  k_xproj<<<dim3(TT / 8, BB), dim3(256), 0, stream>>>(x, WihxT, bih, bhh, Xp);
  k_wdec<<<dim3((int)(((size_t)NP * KP) / 256)), dim3(256), 0, stream>>>(Wdec, Wdb);
  {
    const int TOT = NJ * KK * WKP + NJ * RPB * HH + 2 * BB * NJ * 64 + BB * TT * (KP - HH);
    k_prep<<<dim3((TOT + 255) / 256), dim3(256), 0, stream>>>(Wih, Whh, attWx, WgT,
                                                              WxS, flags, hall);
  }
  {
    const int* a0 = lens; const float* a1 = attb; const float* a2 = attv;
    const float* a3 = WgT; const unsigned short* a4 = WxS;
    const unsigned short* a5 = ETs; const unsigned short* a6 = ctxb;
    const float* a7 = Xp; float* a8 = Hbuf; float* a9 = Pbuf; float* a10 = APbuf;
    unsigned int* a11 = flags; unsigned short* a12 = hall;
    void* args[] = { &a0, &a1, &a2, &a3, &a4, &a5, &a6, &a7, &a8, &a9, &a10, &a11, &a12 };
    hipLaunchCooperativeKernel((void*)k_recur, dim3(BB * NJ), dim3(512), args, 0, stream);
  }
  k_decode<<<dim3(NP / 128, (BB * TT) / 128), dim3(256), 0, stream>>>(hall, Wdb, out);
}

// Round 4
// 919.778 us; speedup vs baseline: 2.8938x; 2.8938x over previous
//
#include <hip/hip_runtime.h>
#include <stdint.h>

#define BB 32
#define TT 64
#define ID 300
#define HH 168
#define SS 512
#define VV 50257
#define G4 672     // 4*H
#define IC 468     // I + C
#define KP 192     // K padded for decode MFMA
#define NP 50304   // V padded to 128
#define NJ 8       // blocks per batch (cluster size)
#define RPB 21     // h rows per block
#define CPB 84     // gate cols per block
#define KK 336     // gate K dim (attn 168 + h 168)
#define WKP 88     // WgT col pad (84 -> 88)
#define EPAD 170   // ETs LDS row pad (168 -> 170; 85 dwords, gcd(85,32)=1 -> conflict-free)
#define SBLK 64    // s positions per block

typedef float f32x4 __attribute__((ext_vector_type(4)));
typedef short bf16x8 __attribute__((ext_vector_type(8)));

__device__ __forceinline__ float bf2f(unsigned short u) {
  union { unsigned int i; float f; } v; v.i = ((unsigned int)u) << 16; return v.f;
}
__device__ __forceinline__ unsigned short f2bf(float f) {
  union { float f; unsigned int u; } v; v.f = f;
  unsigned int r = v.u + 0x7fffu + ((v.u >> 16) & 1u);
  return (unsigned short)(r >> 16);
}
__device__ __forceinline__ float rcpf(float x) { return __builtin_amdgcn_rcpf(x); }

// ---------------- W_ih x-part transpose (for k_xproj) -----------------------
__global__ void k_tr(const float* __restrict__ Wih, float* __restrict__ WihxT) {
  int idx = blockIdx.x * 256 + threadIdx.x;
  if (idx < ID * G4) {
    int k = idx / G4, i = idx - k * G4;
    WihxT[idx] = Wih[(size_t)i * IC + k];
  }
}

// ---------------- seq_proj -> ETs[b][s][h] = bf16(exp(2P)); ctxb bf16 -------
__global__ void k_seqproj(const float* __restrict__ ctx, const float* __restrict__ Ws,
                          unsigned short* __restrict__ ETs, unsigned short* __restrict__ ctxb) {
  const int b = blockIdx.x;
  const int s0 = blockIdx.y * 16;
  const int tid = threadIdx.x;
  __shared__ float ctxL[16 * HH];
  for (int idx = tid; idx < 16 * HH; idx += 256) {
    float v = ctx[(size_t)(b * SS + s0) * HH + idx];
    ctxL[idx] = v;
    ctxb[(size_t)(b * SS + s0) * HH + idx] = f2bf(v);
  }
  __syncthreads();
  #pragma unroll
  for (int o = 0; o < 11; ++o) {
    int idx = o * 256 + tid;
    if (idx < 16 * HH) {
      int s = idx / HH, h = idx - s * HH;
      const float* cr = &ctxL[s * HH];
      float acc = 0.f;
      #pragma unroll 4
      for (int c = 0; c < HH; ++c) acc = fmaf(cr[c], Ws[c * HH + h], acc);
      ETs[(size_t)(b * SS + s0 + s) * HH + h] = f2bf(__expf(2.f * acc));
    }
  }
}

// ---------------- X_proj[b][t][i] = x@WihxT + b_ih + b_hh --------------------
__global__ void k_xproj(const float* __restrict__ x, const float* __restrict__ WihxT,
                        const float* __restrict__ bih, const float* __restrict__ bhh,
                        float* __restrict__ Xp) {
  const int t0 = blockIdx.x * 8;
  const int b = blockIdx.y;
  const int tid = threadIdx.x;
  __shared__ float xL[8 * ID];
  for (int idx = tid; idx < 8 * ID; idx += 256)
    xL[idx] = x[(size_t)(b * TT + t0) * ID + idx];
  __syncthreads();
  for (int i = tid; i < G4; i += 256) {
    float bias = bih[i] + bhh[i];
    float acc[8];
    #pragma unroll
    for (int tt = 0; tt < 8; ++tt) acc[tt] = bias;
    for (int k = 0; k < ID; ++k) {
      float w = WihxT[k * G4 + i];
      #pragma unroll
      for (int tt = 0; tt < 8; ++tt) acc[tt] += xL[tt * ID + k] * w;
    }
    #pragma unroll
    for (int tt = 0; tt < 8; ++tt)
      Xp[(size_t)(b * TT + t0 + tt) * G4 + i] = acc[tt];
  }
}

// ---------------- W_dec -> bf16, padded (NP x KP) ----------------------------
__global__ void k_wdec(const float* __restrict__ Wd, unsigned short* __restrict__ Wdb) {
  size_t idx = (size_t)blockIdx.x * 256 + threadIdx.x;
  int v = (int)(idx / KP), k = (int)(idx - (size_t)v * KP);
  float val = (v < VV && k < HH) ? Wd[(size_t)v * HH + k] : 0.f;
  Wdb[idx] = f2bf(val);
}

// ---------------- WgT [NJ][336][88] fp32, WxS [NJ][21][168] bf16, flags, pad -
__global__ void k_prep(const float* __restrict__ Wih, const float* __restrict__ Whh,
                       const float* __restrict__ attWx, float* __restrict__ WgT,
                       unsigned short* __restrict__ WxS, unsigned int* __restrict__ flags,
                       unsigned short* __restrict__ hall) {
  int idx = blockIdx.x * 256 + threadIdx.x;
  const int T1 = NJ * KK * WKP;            // 236544
  const int T2 = T1 + NJ * RPB * HH;       // +28224
  const int T3 = T2 + 2 * BB * NJ * 64;    // +32768
  const int T4 = T3 + BB * TT * (KP - HH); // +49152
  if (idx < T1) {
    int j = idx / (KK * WKP); int r = idx - j * KK * WKP;
    int k = r / WKP, col = r - k * WKP;
    float w = 0.f;
    if (col < CPB) {
      int gt = col / RPB, rr = col - gt * RPB;
      int gcol = gt * HH + j * RPB + rr;
      w = (k < HH) ? Wih[(size_t)gcol * IC + ID + k] : Whh[(size_t)gcol * HH + (k - HH)];
    }
    WgT[idx] = w;
  } else if (idx < T2) {
    int r = idx - T1;
    WxS[r] = f2bf(attWx[r]);   // [j][row][col] flat == rows j*21.. of attWx
  } else if (idx < T3) {
    flags[idx - T2] = 0u;
  } else if (idx < T4) {
    int r = idx - T3;
    int bt = r / (KP - HH), c = r - bt * (KP - HH);
    hall[(size_t)bt * KP + HH + c] = 0;
  }
}

// ---------------- recurrence: 8 blocks per batch, flag-sync, NO cache inval --
__global__ __launch_bounds__(512, 1) void k_recur(
    const int* __restrict__ lens, const float* __restrict__ attb,
    const float* __restrict__ attv, const float* __restrict__ WgT,
    const unsigned short* __restrict__ WxS, const unsigned short* __restrict__ ETs,
    const unsigned short* __restrict__ ctxb, const float* __restrict__ Xp,
    float* __restrict__ Hbuf, float* __restrict__ Pbuf, float* __restrict__ APbuf,
    unsigned int* __restrict__ flags, unsigned short* __restrict__ hall) {
  const int b = blockIdx.x & 31;
  const int j = blockIdx.x >> 5;
  const int tid = threadIdx.x;

  __shared__ float WgL[KK][WKP];            // 118272 B, transposed [k][col]
  __shared__ unsigned short EL[SBLK][EPAD]; // 21760 B
  __shared__ unsigned short WxL[RPB][HH];   // 7056 B
  __shared__ float scratch[512];
  __shared__ float redH[504], redC[504];
  __shared__ float gE[HH], hsh[HH], abL[HH], vL[HH], attn[HH];
  __shared__ float esh[SBLK], gatesL[CPB], hLoc[RPB], cLoc[RPB];
  __shared__ float denr_s, sumv_s, bsum_s;

  // ---- stage static data
  {
    const f32x4* src = (const f32x4*)(WgT + (size_t)j * KK * WKP);
    f32x4* dst = (f32x4*)WgL;
    for (int i = tid; i < KK * WKP / 4; i += 512) dst[i] = src[i];
  }
  for (int i = tid; i < SBLK * HH; i += 512) {
    int s = i / HH, h = i - s * HH;
    EL[s][h] = ETs[((size_t)b * SS + j * SBLK + s) * HH + h];
  }
  for (int i = tid; i < RPB * HH; i += 512)
    ((unsigned short*)WxL)[i] = WxS[(size_t)j * RPB * HH + i];
  if (tid < HH) { abL[tid] = attb[tid]; vL[tid] = attv[tid]; }
  if (tid < RPB) cLoc[tid] = 0.f;
  __syncthreads();
  if (tid == 0) {
    float s = 0.f;
    for (int h = 0; h < HH; ++h) s += vL[h];
    sumv_s = s;
  }
  const int len = lens[b];
  const int sbase = j * SBLK;
  unsigned int* fB = flags + (size_t)(b * NJ) * 64;
  unsigned int* fA = flags + (size_t)BB * NJ * 64 + (size_t)(b * NJ) * 64;
  __syncthreads();

  for (int t = 0; t < TT; ++t) {
    // ---- 1/2: sync on h (flagB) + build gE, hsh
    if (t > 0) {
      if (tid < NJ) {
        int g = 0;
        while (__hip_atomic_load(&fB[tid * 64], __ATOMIC_RELAXED,
                                 __HIP_MEMORY_SCOPE_AGENT) < (unsigned)t) {
          __builtin_amdgcn_s_sleep(2);
          if (++g > (1 << 27)) break;
        }
      }
      asm volatile("" ::: "memory");
      __syncthreads();
      if (tid < HH) {
        float a = abL[tid];
        #pragma unroll
        for (int jj = 0; jj < NJ; ++jj)
          a += __hip_atomic_load(&APbuf[((size_t)b * NJ + jj) * HH + tid],
                                 __ATOMIC_RELAXED, __HIP_MEMORY_SCOPE_AGENT);
        gE[tid] = __expf(2.f * a);
        hsh[tid] = __hip_atomic_load(&Hbuf[(size_t)b * HH + tid],
                                     __ATOMIC_RELAXED, __HIP_MEMORY_SCOPE_AGENT);
      }
    } else {
      if (tid < HH) { gE[tid] = __expf(2.f * abL[tid]); hsh[tid] = 0.f; }
    }
    __syncthreads();
    // ---- 3: B: e-partials over own s-range (LDS-resident E)
    {
      int sl = tid & 63, hs = tid >> 6;
      const unsigned short* er = &EL[sl][hs * RPB];
      const int hb = hs * RPB;
      float ep = 0.f;
      #pragma unroll 7
      for (int i = 0; i < RPB; ++i)
        ep += vL[hb + i] * rcpf(fmaf(gE[hb + i], bf2f(er[i]), 1.f));
      scratch[hs * 64 + sl] = ep;
    }
    __syncthreads();
    if (tid < SBLK) {
      float tot = 0.f;
      #pragma unroll
      for (int hs = 0; hs < 8; ++hs) tot += scratch[hs * 64 + tid];
      float eh = (sbase + tid < len) ? __expf(sumv_s - 2.f * tot) : 0.f;
      esh[tid] = eh;
      float r = eh;
      #pragma unroll
      for (int off = 32; off; off >>= 1) r += __shfl_down(r, off);
      if (tid == 0) bsum_s = r;
    }
    __syncthreads();
    // ---- 4: C: weighted-context partials (ctxb now L2-hot: no invalidates)
    if (tid < 504) {
      int c = tid % HH, ch = tid / HH;
      const unsigned short* cb = ctxb + ((size_t)b * SS + sbase) * HH + c;
      float p = 0.f;
      for (int s = ch; s < SBLK; s += 3)
        p = fmaf(esh[s], bf2f(cb[(size_t)s * HH]), p);
      scratch[ch * HH + c] = p;
    }
    __syncthreads();
    if (tid < HH) {
      float p = scratch[tid] + scratch[HH + tid] + scratch[2 * HH + tid];
      __hip_atomic_store(&Pbuf[((size_t)b * NJ + j) * 176 + tid], p,
                         __ATOMIC_RELAXED, __HIP_MEMORY_SCOPE_AGENT);
    } else if (tid == HH) {
      __hip_atomic_store(&Pbuf[((size_t)b * NJ + j) * 176 + HH], bsum_s,
                         __ATOMIC_RELAXED, __HIP_MEMORY_SCOPE_AGENT);
    }
    __syncthreads();   // drains each wave's vmem (compiler emits vmcnt(0) before s_barrier)
    if (tid == 0) {
      asm volatile("s_waitcnt vmcnt(0)" ::: "memory");
      __hip_atomic_store(&fA[j * 64], (unsigned)(t + 1),
                         __ATOMIC_RELAXED, __HIP_MEMORY_SCOPE_AGENT);
    }
    // ---- 5: D_h (overlaps flagA propagation): Wh @ h_{t-1}
    if (tid < 504) {
      int col = tid % CPB, kc = tid / CPB;
      int k0 = HH + kc * 28;
      float acc = 0.f;
      #pragma unroll 7
      for (int i = 0; i < 28; ++i)
        acc = fmaf(WgL[k0 + i][col], hsh[kc * 28 + i], acc);
      redH[kc * CPB + col] = acc;
    }
    // ---- 6: poll flagA
    if (tid < NJ) {
      int g = 0;
      while (__hip_atomic_load(&fA[tid * 64], __ATOMIC_RELAXED,
                               __HIP_MEMORY_SCOPE_AGENT) < (unsigned)(t + 1)) {
        __builtin_amdgcn_s_sleep(2);
        if (++g > (1 << 27)) break;
      }
    }
    asm volatile("" ::: "memory");
    __syncthreads();
    // ---- 7: reduce partials -> attn
    if (tid < HH + 1) {
      float s = 0.f;
      #pragma unroll
      for (int jj = 0; jj < NJ; ++jj)
        s += __hip_atomic_load(&Pbuf[((size_t)b * NJ + jj) * 176 + tid],
                               __ATOMIC_RELAXED, __HIP_MEMORY_SCOPE_AGENT);
      if (tid < HH) scratch[tid] = s;
      else denr_s = 1.f / s;
    }
    __syncthreads();
    if (tid < HH) attn[tid] = scratch[tid] * denr_s;
    __syncthreads();
    // ---- 8: D_c: Wc @ attn
    if (tid < 504) {
      int col = tid % CPB, kc = tid / CPB;
      int k0 = kc * 28;
      float acc = 0.f;
      #pragma unroll 7
      for (int i = 0; i < 28; ++i)
        acc = fmaf(WgL[k0 + i][col], attn[k0 + i], acc);
      redC[kc * CPB + col] = acc;
    }
    __syncthreads();
    // ---- 9: gates + LSTM update
    if (tid < CPB) {
      int gt = tid / RPB, rr = tid - gt * RPB;
      int gcol = gt * HH + j * RPB + rr;
      float g = Xp[((size_t)b * TT + t) * G4 + gcol];
      #pragma unroll
      for (int kc = 0; kc < 6; ++kc) g += redH[kc * CPB + tid] + redC[kc * CPB + tid];
      gatesL[tid] = g;
    }
    __syncthreads();
    if (tid < RPB) {
      float ig = gatesL[tid], fg = gatesL[RPB + tid];
      float gg = gatesL[2 * RPB + tid], og = gatesL[3 * RPB + tid];
      float si = rcpf(1.f + __expf(-ig));
      float sf = rcpf(1.f + __expf(-fg));
      float so = rcpf(1.f + __expf(-og));
      float tg = 1.f - 2.f * rcpf(1.f + __expf(2.f * gg));
      float cn = fmaf(sf, cLoc[tid], si * tg);
      float tc = 1.f - 2.f * rcpf(1.f + __expf(2.f * cn));
      float hn = so * tc;
      cLoc[tid] = cn; hLoc[tid] = hn;
      hall[((size_t)b * TT + t) * KP + j * RPB + tid] = f2bf(hn);
      __hip_atomic_store(&Hbuf[(size_t)b * HH + j * RPB + tid], hn,
                         __ATOMIC_RELAXED, __HIP_MEMORY_SCOPE_AGENT);
    }
    __syncthreads();
    // ---- 10: a_j = h_slice @ Wx_slice, post + flagB
    if (tid < 504) {
      int col = tid % HH, ch = tid / HH;
      float acc = 0.f;
      #pragma unroll
      for (int r = ch * 7; r < ch * 7 + 7; ++r)
        acc = fmaf(hLoc[r], bf2f(WxL[r][col]), acc);
      scratch[ch * HH + col] = acc;
    }
    __syncthreads();
    if (tid < HH) {
      float a = scratch[tid] + scratch[HH + tid] + scratch[2 * HH + tid];
      __hip_atomic_store(&APbuf[((size_t)b * NJ + j) * HH + tid], a,
                         __ATOMIC_RELAXED, __HIP_MEMORY_SCOPE_AGENT);
    }
    __syncthreads();   // drains each wave's vmem before the flag
    if (tid == 0) {
      asm volatile("s_waitcnt vmcnt(0)" ::: "memory");
      __hip_atomic_store(&fB[j * 64], (unsigned)(t + 1),
                         __ATOMIC_RELAXED, __HIP_MEMORY_SCOPE_AGENT);
    }
  }
}

// ---------------- decode GEMM: out = hall(2048xKP) @ Wdb(NPxKP)^T -----------
__global__ __launch_bounds__(256) void k_decode(const unsigned short* __restrict__ hallb,
                                                const unsigned short* __restrict__ wdb,
                                                float* __restrict__ out) {
  __shared__ __align__(16) unsigned short As[128 * 64];
  __shared__ __align__(16) unsigned short Bs[128 * 64];
  const int tid = threadIdx.x;
  const int n0 = blockIdx.x * 128, m0 = blockIdx.y * 128;
  const int lane = tid & 63, wid = tid >> 6;
  const int wm = wid >> 1, wn = wid & 1;
  const int lr = lane & 15, lk = lane >> 4;
  f32x4 acc[4][4];
  #pragma unroll
  for (int i = 0; i < 4; ++i)
    #pragma unroll
    for (int jj = 0; jj < 4; ++jj) acc[i][jj] = (f32x4)0.f;

  for (int k0 = 0; k0 < KP; k0 += 64) {
    if (k0) __syncthreads();
    #pragma unroll
    for (int i = 0; i < 4; ++i) {
      int flat = i * 256 + tid;
      int row = flat >> 3;
      int col = (flat & 7) * 8;
      uint4 va = *(const uint4*)(hallb + (size_t)(m0 + row) * KP + k0 + col);
      *(uint4*)&As[row * 64 + col] = va;
      uint4 vb = *(const uint4*)(wdb + (size_t)(n0 + row) * KP + k0 + col);
      *(uint4*)&Bs[row * 64 + col] = vb;
    }
    __syncthreads();
    #pragma unroll
    for (int kk = 0; kk < 64; kk += 32) {
      bf16x8 af[4], bfr[4];
      #pragma unroll
      for (int mi = 0; mi < 4; ++mi)
        af[mi] = *(const bf16x8*)&As[(wm * 64 + mi * 16 + lr) * 64 + kk + lk * 8];
      #pragma unroll
      for (int ni = 0; ni < 4; ++ni)
        bfr[ni] = *(const bf16x8*)&Bs[(wn * 64 + ni * 16 + lr) * 64 + kk + lk * 8];
      #pragma unroll
      for (int mi = 0; mi < 4; ++mi)
        #pragma unroll
        for (int ni = 0; ni < 4; ++ni)
          acc[mi][ni] = __builtin_amdgcn_mfma_f32_16x16x32_bf16(
              af[mi], bfr[ni], acc[mi][ni], 0, 0, 0);
    }
  }
  #pragma unroll
  for (int mi = 0; mi < 4; ++mi)
    #pragma unroll
    for (int ni = 0; ni < 4; ++ni) {
      int col = n0 + wn * 64 + ni * 16 + lr;
      if (col < VV) {
        #pragma unroll
        for (int r = 0; r < 4; ++r) {
          int row = m0 + wm * 64 + mi * 16 + lk * 4 + r;
          out[(size_t)row * VV + col] = acc[mi][ni][r];
        }
      }
    }
}

extern "C" void kernel_launch(void* const* d_in, const int* in_sizes, int n_in,
                              void* d_out, int out_size, void* d_ws, size_t ws_size,
                              hipStream_t stream) {
  (void)in_sizes; (void)n_in; (void)out_size; (void)ws_size;
  const float* x     = (const float*)d_in[0];
  const float* ctx   = (const float*)d_in[1];
  const int*   lens  = (const int*)d_in[2];
  const float* Wih   = (const float*)d_in[3];
  const float* Whh   = (const float*)d_in[4];
  const float* bih   = (const float*)d_in[5];
  const float* bhh   = (const float*)d_in[6];
  const float* attWx = (const float*)d_in[7];
  const float* attWs = (const float*)d_in[8];
  const float* attb  = (const float*)d_in[9];
  const float* attv  = (const float*)d_in[10];
  const float* Wdec  = (const float*)d_in[11];
  float* out = (float*)d_out;

  char* base = (char*)d_ws;
  size_t off = 0;
  auto alloc = [&](size_t bytes) -> void* {
    off = (off + 255) & ~(size_t)255;
    void* p = base + off;
    off += bytes;
    return p;
  };
  unsigned short* ETs  = (unsigned short*)alloc((size_t)BB * SS * HH * 2);
  unsigned short* ctxb = (unsigned short*)alloc((size_t)BB * SS * HH * 2);
  float*          Xp   = (float*)alloc((size_t)BB * TT * G4 * 4);
  float*          WihxT= (float*)alloc((size_t)ID * G4 * 4);
  unsigned short* hall = (unsigned short*)alloc((size_t)BB * TT * KP * 2);
  unsigned short* Wdb  = (unsigned short*)alloc((size_t)NP * KP * 2);
  float*          WgT  = (float*)alloc((size_t)NJ * KK * WKP * 4);
  unsigned short* WxS  = (unsigned short*)alloc((size_t)NJ * RPB * HH * 2);
  float*          Hbuf = (float*)alloc((size_t)BB * HH * 4);
  float*          Pbuf = (float*)alloc((size_t)BB * NJ * 176 * 4);
  float*          APbuf= (float*)alloc((size_t)BB * NJ * HH * 4);
  unsigned int*   flags= (unsigned int*)alloc((size_t)2 * BB * NJ * 64 * 4);

  k_tr<<<dim3((ID * G4 + 255) / 256), dim3(256), 0, stream>>>(Wih, WihxT);
  k_seqproj<<<dim3(BB, SS / 16), dim3(256), 0, stream>>>(ctx, attWs, ETs, ctxb);
  k_xproj<<<dim3(TT / 8, BB), dim3(256), 0, stream>>>(x, WihxT, bih, bhh, Xp);
  k_wdec<<<dim3((int)(((size_t)NP * KP) / 256)), dim3(256), 0, stream>>>(Wdec, Wdb);
  {
    const int TOT = NJ * KK * WKP + NJ * RPB * HH + 2 * BB * NJ * 64 + BB * TT * (KP - HH);
    k_prep<<<dim3((TOT + 255) / 256), dim3(256), 0, stream>>>(Wih, Whh, attWx, WgT,
                                                              WxS, flags, hall);
  }
  {
    const int* a0 = lens; const float* a1 = attb; const float* a2 = attv;
    const float* a3 = WgT; const unsigned short* a4 = WxS;
    const unsigned short* a5 = ETs; const unsigned short* a6 = ctxb;
    const float* a7 = Xp; float* a8 = Hbuf; float* a9 = Pbuf; float* a10 = APbuf;
    unsigned int* a11 = flags; unsigned short* a12 = hall;
    void* args[] = { &a0, &a1, &a2, &a3, &a4, &a5, &a6, &a7, &a8, &a9, &a10, &a11, &a12 };
    hipLaunchCooperativeKernel((void*)k_recur, dim3(BB * NJ), dim3(512), args, 0, stream);
  }
  k_decode<<<dim3(NP / 128, (BB * TT) / 128), dim3(256), 0, stream>>>(hall, Wdb, out);
}

// Round 5
// 814.089 us; speedup vs baseline: 3.2695x; 1.1298x over previous
//
#include <hip/hip_runtime.h>
#include <stdint.h>

#define BB 32
#define TT 64
#define ID 300
#define HH 168
#define SS 512
#define VV 50257
#define G4 672     // 4*H
#define IC 468     // I + C
#define KP 192     // K padded for decode MFMA
#define NP2 50432  // V padded to 256 (197 tiles)
#define NJ 8       // blocks per batch (cluster size)
#define RPB 21     // h rows per block
#define CPB 84     // gate cols per block
#define KK 336     // gate K dim (attn 168 + h 168)
#define WKP 88     // WgT col pad
#define EPAD 170   // ETs LDS row pad (85 dwords, gcd(85,32)=1 -> conflict-free)
#define SBLK 64    // s positions per block
#define LP 72      // decode LDS row pad in shorts (36 dwords, 2-way banks = free)

typedef float f32x4 __attribute__((ext_vector_type(4)));
typedef short bf16x8 __attribute__((ext_vector_type(8)));

__device__ __forceinline__ float bf2f(unsigned short u) {
  union { unsigned int i; float f; } v; v.i = ((unsigned int)u) << 16; return v.f;
}
__device__ __forceinline__ unsigned short f2bf(float f) {
  union { float f; unsigned int u; } v; v.f = f;
  unsigned int r = v.u + 0x7fffu + ((v.u >> 16) & 1u);
  return (unsigned short)(r >> 16);
}
__device__ __forceinline__ float rcpf(float x) { return __builtin_amdgcn_rcpf(x); }

// ============ prep-all: Wdb (vectorized), WihxT transpose, WgT/WxS/flags/pad =
#define NB_WDEC 4728   // NP2*KP/8/256
#define NB_TR   788    // ceil(ID*G4/256)
__global__ void k_prepall(const float* __restrict__ Wih, const float* __restrict__ Whh,
                          const float* __restrict__ attWx, const float* __restrict__ Wd,
                          float* __restrict__ WihxT, unsigned short* __restrict__ Wdb,
                          float* __restrict__ WgT, unsigned short* __restrict__ WxS,
                          unsigned int* __restrict__ flags, unsigned short* __restrict__ hall) {
  const int bid = blockIdx.x, tid = threadIdx.x;
  if (bid < NB_WDEC) {
    // Wdb[v][k] = bf16(Wd[v][k]), 8 elems/thread
    size_t e0 = ((size_t)bid * 256 + tid) * 8;
    int v = (int)(e0 / KP), k = (int)(e0 - (size_t)v * KP);
    unsigned short o[8];
    if (v < VV && k < HH) {
      const float* src = Wd + (size_t)v * HH + k;
      #pragma unroll
      for (int i = 0; i < 8; ++i) o[i] = f2bf(src[i]);
    } else {
      #pragma unroll
      for (int i = 0; i < 8; ++i) o[i] = 0;
    }
    *(uint4*)(Wdb + e0) = *(const uint4*)o;
    return;
  }
  if (bid < NB_WDEC + NB_TR) {
    int idx = (bid - NB_WDEC) * 256 + tid;
    if (idx < ID * G4) {
      int k = idx / G4, i = idx - k * G4;
      WihxT[idx] = Wih[(size_t)i * IC + k];
    }
    return;
  }
  int idx = (bid - NB_WDEC - NB_TR) * 256 + tid;
  const int T1 = NJ * KK * WKP;            // 236544
  const int T2 = T1 + NJ * RPB * HH;       // +28224
  const int T3 = T2 + 2 * BB * NJ * 64;    // +32768
  const int T4 = T3 + BB * TT * (KP - HH); // +49152
  if (idx < T1) {
    int j = idx / (KK * WKP); int r = idx - j * (KK * WKP);
    int k = r / WKP, col = r - k * WKP;
    float w = 0.f;
    if (col < CPB) {
      int gt = col / RPB, rr = col - gt * RPB;
      int gcol = gt * HH + j * RPB + rr;
      w = (k < HH) ? Wih[(size_t)gcol * IC + ID + k] : Whh[(size_t)gcol * HH + (k - HH)];
    }
    WgT[idx] = w;
  } else if (idx < T2) {
    int r = idx - T1;
    WxS[r] = f2bf(attWx[r]);
  } else if (idx < T3) {
    flags[idx - T2] = 0u;
  } else if (idx < T4) {
    int r = idx - T3;
    int bt = r / (KP - HH), c = r - bt * (KP - HH);
    hall[(size_t)bt * KP + HH + c] = 0;
  }
}

// ============ seqproj (blocks 0..1023) + xproj (blocks 1024..1279) ===========
__global__ void k_seqxp(const float* __restrict__ ctx, const float* __restrict__ Ws,
                        const float* __restrict__ x, const float* __restrict__ WihxT,
                        const float* __restrict__ bih, const float* __restrict__ bhh,
                        unsigned short* __restrict__ ETs, unsigned short* __restrict__ ctxb,
                        float* __restrict__ Xp) {
  __shared__ float sbuf[2688];
  const int tid = threadIdx.x;
  if (blockIdx.x < 1024) {
    const int b = blockIdx.x & 31;
    const int s0 = (blockIdx.x >> 5) * 16;
    for (int idx = tid; idx < 16 * HH; idx += 256) {
      float v = ctx[(size_t)(b * SS + s0) * HH + idx];
      sbuf[idx] = v;
      ctxb[(size_t)(b * SS + s0) * HH + idx] = f2bf(v);
    }
    __syncthreads();
    #pragma unroll
    for (int o = 0; o < 11; ++o) {
      int idx = o * 256 + tid;
      if (idx < 16 * HH) {
        int s = idx / HH, h = idx - s * HH;
        const float* cr = &sbuf[s * HH];
        float acc = 0.f;
        #pragma unroll 4
        for (int c = 0; c < HH; ++c) acc = fmaf(cr[c], Ws[c * HH + h], acc);
        ETs[(size_t)(b * SS + s0 + s) * HH + h] = f2bf(__expf(2.f * acc));
      }
    }
  } else {
    const int r = blockIdx.x - 1024;
    const int t0 = (r & 7) * 8;
    const int b = r >> 3;
    for (int idx = tid; idx < 8 * ID; idx += 256)
      sbuf[idx] = x[(size_t)(b * TT + t0) * ID + idx];
    __syncthreads();
    for (int i = tid; i < G4; i += 256) {
      float bias = bih[i] + bhh[i];
      float acc[8];
      #pragma unroll
      for (int tt = 0; tt < 8; ++tt) acc[tt] = bias;
      for (int k = 0; k < ID; ++k) {
        float w = WihxT[k * G4 + i];
        #pragma unroll
        for (int tt = 0; tt < 8; ++tt) acc[tt] += sbuf[tt * ID + k] * w;
      }
      #pragma unroll
      for (int tt = 0; tt < 8; ++tt)
        Xp[(size_t)(b * TT + t0 + tt) * G4 + i] = acc[tt];
    }
  }
}

// ============ recurrence: 8 blocks/batch, flag-sync, 11-barrier step =========
__global__ __launch_bounds__(512, 1) void k_recur(
    const int* __restrict__ lens, const float* __restrict__ attb,
    const float* __restrict__ attv, const float* __restrict__ WgT,
    const unsigned short* __restrict__ WxS, const unsigned short* __restrict__ ETs,
    const unsigned short* __restrict__ ctxb, const float* __restrict__ Xp,
    float* __restrict__ Hbuf, float* __restrict__ Pbuf, float* __restrict__ APbuf,
    unsigned int* __restrict__ flags, unsigned short* __restrict__ hall) {
  const int b = blockIdx.x & 31;
  const int j = blockIdx.x >> 5;
  const int tid = threadIdx.x;

  __shared__ float WgL[KK][WKP];            // 118272 B, [k][col]
  __shared__ unsigned short EL[SBLK][EPAD]; // 21760 B
  __shared__ unsigned short WxL[RPB][HH];   // 7056 B
  __shared__ float scratch[512];
  __shared__ float redH[504], redC[504];
  __shared__ float gE[HH], hsh[HH], abL[HH], vL[HH], attn[HH];
  __shared__ float esh[SBLK], hLoc[RPB], cLoc[RPB], wsum[8];
  __shared__ float sumv_s, bsum_s;

  {
    const f32x4* src = (const f32x4*)(WgT + (size_t)j * KK * WKP);
    f32x4* dst = (f32x4*)WgL;
    for (int i = tid; i < KK * WKP / 4; i += 512) dst[i] = src[i];
  }
  for (int i = tid; i < SBLK * HH; i += 512) {
    int s = i / HH, h = i - s * HH;
    EL[s][h] = ETs[((size_t)b * SS + j * SBLK + s) * HH + h];
  }
  for (int i = tid; i < RPB * HH; i += 512)
    ((unsigned short*)WxL)[i] = WxS[(size_t)j * RPB * HH + i];
  if (tid < HH) { abL[tid] = attb[tid]; vL[tid] = attv[tid]; }
  if (tid < RPB) cLoc[tid] = 0.f;
  __syncthreads();
  if (tid == 0) {
    float s = 0.f;
    for (int h = 0; h < HH; ++h) s += vL[h];
    sumv_s = s;
  }
  const int len = lens[b];
  const int sbase = j * SBLK;
  unsigned int* fB = flags + (size_t)(b * NJ) * 64;
  unsigned int* fA = flags + (size_t)BB * NJ * 64 + (size_t)(b * NJ) * 64;
  __syncthreads();

  for (int t = 0; t < TT; ++t) {
    // prefetch Xp gates for this block's 21 rows (consumed late)
    float xpr0 = 0.f, xpr1 = 0.f, xpr2 = 0.f, xpr3 = 0.f;
    if (tid < RPB) {
      const float* xp = Xp + ((size_t)b * TT + t) * G4 + j * RPB + tid;
      xpr0 = xp[0]; xpr1 = xp[HH]; xpr2 = xp[2 * HH]; xpr3 = xp[3 * HH];
    }
    // ---- h-sync + gE
    if (t > 0) {
      if (tid < NJ) {
        int g = 0;
        while (__hip_atomic_load(&fB[tid * 64], __ATOMIC_RELAXED,
                                 __HIP_MEMORY_SCOPE_AGENT) < (unsigned)t) {
          __builtin_amdgcn_s_sleep(2);
          if (++g > (1 << 27)) break;
        }
      }
      asm volatile("" ::: "memory");
      __syncthreads();                                   // BAR1
    }
    if (tid < HH) {
      float a = abL[tid];
      if (t > 0) {
        #pragma unroll
        for (int jj = 0; jj < NJ; ++jj)
          a += __hip_atomic_load(&APbuf[((size_t)b * NJ + jj) * HH + tid],
                                 __ATOMIC_RELAXED, __HIP_MEMORY_SCOPE_AGENT);
        hsh[tid] = __hip_atomic_load(&Hbuf[(size_t)b * HH + tid],
                                     __ATOMIC_RELAXED, __HIP_MEMORY_SCOPE_AGENT);
      } else {
        hsh[tid] = 0.f;
      }
      gE[tid] = __expf(2.f * a);
    }
    __syncthreads();                                     // BAR2
    // ---- B + softmax (wave-local, no barriers inside)
    {
      int w = tid >> 6, lane = tid & 63;
      int sl = w * 8 + (lane >> 3);
      int hg = lane & 7;
      const unsigned short* er = &EL[sl][hg * RPB];
      const int hb = hg * RPB;
      float ep = 0.f;
      #pragma unroll 7
      for (int i = 0; i < RPB; ++i)
        ep += vL[hb + i] * rcpf(fmaf(gE[hb + i], bf2f(er[i]), 1.f));
      ep += __shfl_xor(ep, 1); ep += __shfl_xor(ep, 2); ep += __shfl_xor(ep, 4);
      float eh = (sbase + sl < len) ? __expf(sumv_s - 2.f * ep) : 0.f;
      float ws = (hg == 0) ? eh : 0.f;
      ws += __shfl_xor(ws, 8); ws += __shfl_xor(ws, 16); ws += __shfl_xor(ws, 32);
      if (lane == 0) wsum[w] = ws;
      if (hg == 0) esh[sl] = eh;
    }
    __syncthreads();                                     // BAR3
    // ---- C partials + bsum
    if (tid < 504) {
      int c = tid % HH, ch = tid / HH;
      const unsigned short* cb = ctxb + ((size_t)b * SS + sbase) * HH + c;
      float p = 0.f;
      for (int s = ch; s < SBLK; s += 3)
        p = fmaf(esh[s], bf2f(cb[(size_t)s * HH]), p);
      scratch[ch * HH + c] = p;
    } else if (tid == 504) {
      float bs = 0.f;
      #pragma unroll
      for (int w = 0; w < 8; ++w) bs += wsum[w];
      bsum_s = bs;
    }
    __syncthreads();                                     // BAR4
    if (tid < HH) {
      float p = scratch[tid] + scratch[HH + tid] + scratch[2 * HH + tid];
      __hip_atomic_store(&Pbuf[((size_t)b * NJ + j) * 176 + tid], p,
                         __ATOMIC_RELAXED, __HIP_MEMORY_SCOPE_AGENT);
    } else if (tid == HH) {
      __hip_atomic_store(&Pbuf[((size_t)b * NJ + j) * 176 + HH], bsum_s,
                         __ATOMIC_RELAXED, __HIP_MEMORY_SCOPE_AGENT);
    }
    __syncthreads();                                     // BAR5 (drains stores)
    if (tid == 0) {
      asm volatile("s_waitcnt vmcnt(0)" ::: "memory");
      __hip_atomic_store(&fA[j * 64], (unsigned)(t + 1),
                         __ATOMIC_RELAXED, __HIP_MEMORY_SCOPE_AGENT);
    }
    // ---- D_h (overlaps flagA propagation)
    if (tid < 504) {
      int col = tid % CPB, kc = tid / CPB;
      int k0 = HH + kc * 28;
      float acc = 0.f;
      #pragma unroll 7
      for (int i = 0; i < 28; ++i)
        acc = fmaf(WgL[k0 + i][col], hsh[kc * 28 + i], acc);
      redH[kc * CPB + col] = acc;
    }
    // ---- poll flagA
    if (tid < NJ) {
      int g = 0;
      while (__hip_atomic_load(&fA[tid * 64], __ATOMIC_RELAXED,
                               __HIP_MEMORY_SCOPE_AGENT) < (unsigned)(t + 1)) {
        __builtin_amdgcn_s_sleep(2);
        if (++g > (1 << 27)) break;
      }
    }
    asm volatile("" ::: "memory");
    __syncthreads();                                     // BAR6
    // ---- attn finalize (per-thread denominator; no extra barrier)
    if (tid < HH) {
      float s = 0.f, den = 0.f;
      #pragma unroll
      for (int jj = 0; jj < NJ; ++jj) {
        const float* pb = &Pbuf[((size_t)b * NJ + jj) * 176];
        s += __hip_atomic_load(&pb[tid], __ATOMIC_RELAXED, __HIP_MEMORY_SCOPE_AGENT);
        den += __hip_atomic_load(&pb[HH], __ATOMIC_RELAXED, __HIP_MEMORY_SCOPE_AGENT);
      }
      attn[tid] = s * rcpf(den);
    }
    __syncthreads();                                     // BAR7
    // ---- D_c
    if (tid < 504) {
      int col = tid % CPB, kc = tid / CPB;
      int k0 = kc * 28;
      float acc = 0.f;
      #pragma unroll 7
      for (int i = 0; i < 28; ++i)
        acc = fmaf(WgL[k0 + i][col], attn[k0 + i], acc);
      redC[kc * CPB + col] = acc;
    }
    __syncthreads();                                     // BAR8
    // ---- gates + LSTM (21 threads, merged)
    if (tid < RPB) {
      float g0 = xpr0, g1 = xpr1, g2 = xpr2, g3 = xpr3;
      #pragma unroll
      for (int kc = 0; kc < 6; ++kc) {
        const float* rh = &redH[kc * CPB];
        const float* rc = &redC[kc * CPB];
        g0 += rh[tid] + rc[tid];
        g1 += rh[RPB + tid] + rc[RPB + tid];
        g2 += rh[2 * RPB + tid] + rc[2 * RPB + tid];
        g3 += rh[3 * RPB + tid] + rc[3 * RPB + tid];
      }
      float si = rcpf(1.f + __expf(-g0));
      float sf = rcpf(1.f + __expf(-g1));
      float tg = 1.f - 2.f * rcpf(1.f + __expf(2.f * g2));
      float so = rcpf(1.f + __expf(-g3));
      float cn = fmaf(sf, cLoc[tid], si * tg);
      float tc = 1.f - 2.f * rcpf(1.f + __expf(2.f * cn));
      float hn = so * tc;
      cLoc[tid] = cn; hLoc[tid] = hn;
      hall[((size_t)b * TT + t) * KP + j * RPB + tid] = f2bf(hn);
      __hip_atomic_store(&Hbuf[(size_t)b * HH + j * RPB + tid], hn,
                         __ATOMIC_RELAXED, __HIP_MEMORY_SCOPE_AGENT);
    }
    __syncthreads();                                     // BAR9
    // ---- a_j = h_slice @ Wx_slice
    if (tid < 504) {
      int col = tid % HH, ch = tid / HH;
      float acc = 0.f;
      #pragma unroll
      for (int r = ch * 7; r < ch * 7 + 7; ++r)
        acc = fmaf(hLoc[r], bf2f(WxL[r][col]), acc);
      scratch[ch * HH + col] = acc;
    }
    __syncthreads();                                     // BAR10
    if (tid < HH) {
      float a = scratch[tid] + scratch[HH + tid] + scratch[2 * HH + tid];
      __hip_atomic_store(&APbuf[((size_t)b * NJ + j) * HH + tid], a,
                         __ATOMIC_RELAXED, __HIP_MEMORY_SCOPE_AGENT);
    }
    __syncthreads();                                     // BAR11 (drains stores)
    if (tid == 0) {
      asm volatile("s_waitcnt vmcnt(0)" ::: "memory");
      __hip_atomic_store(&fB[j * 64], (unsigned)(t + 1),
                         __ATOMIC_RELAXED, __HIP_MEMORY_SCOPE_AGENT);
    }
  }
}

// ============ decode GEMM: 256x256 tiles, 512 threads ========================
__global__ __launch_bounds__(512, 1) void k_decode(const unsigned short* __restrict__ hallb,
                                                   const unsigned short* __restrict__ wdb,
                                                   float* __restrict__ out) {
  __shared__ __align__(16) unsigned short As[256 * LP];
  __shared__ __align__(16) unsigned short Bs[256 * LP];
  const int tid = threadIdx.x;
  const int n0 = blockIdx.x * 256, m0 = blockIdx.y * 256;
  const int lane = tid & 63, wid = tid >> 6;
  const int wm = wid >> 2, wn = wid & 3;
  const int lr = lane & 15, lk = lane >> 4;
  f32x4 acc[8][4];
  #pragma unroll
  for (int i = 0; i < 8; ++i)
    #pragma unroll
    for (int jj = 0; jj < 4; ++jj) acc[i][jj] = (f32x4)0.f;

  for (int k0 = 0; k0 < KP; k0 += 64) {
    if (k0) __syncthreads();
    #pragma unroll
    for (int i = 0; i < 4; ++i) {
      int flat = i * 512 + tid;
      int row = flat >> 3;
      int c8 = flat & 7;
      uint4 va = *(const uint4*)(hallb + (size_t)(m0 + row) * KP + k0 + c8 * 8);
      *(uint4*)&As[row * LP + c8 * 8] = va;
      uint4 vb = *(const uint4*)(wdb + (size_t)(n0 + row) * KP + k0 + c8 * 8);
      *(uint4*)&Bs[row * LP + c8 * 8] = vb;
    }
    __syncthreads();
    #pragma unroll
    for (int kk = 0; kk < 64; kk += 32) {
      bf16x8 af[8], bfr[4];
      #pragma unroll
      for (int mi = 0; mi < 8; ++mi)
        af[mi] = *(const bf16x8*)&As[(wm * 128 + mi * 16 + lr) * LP + kk + lk * 8];
      #pragma unroll
      for (int ni = 0; ni < 4; ++ni)
        bfr[ni] = *(const bf16x8*)&Bs[(wn * 64 + ni * 16 + lr) * LP + kk + lk * 8];
      #pragma unroll
      for (int mi = 0; mi < 8; ++mi)
        #pragma unroll
        for (int ni = 0; ni < 4; ++ni)
          acc[mi][ni] = __builtin_amdgcn_mfma_f32_16x16x32_bf16(
              af[mi], bfr[ni], acc[mi][ni], 0, 0, 0);
    }
  }
  #pragma unroll
  for (int mi = 0; mi < 8; ++mi)
    #pragma unroll
    for (int ni = 0; ni < 4; ++ni) {
      int col = n0 + wn * 64 + ni * 16 + lr;
      if (col < VV) {
        #pragma unroll
        for (int r = 0; r < 4; ++r) {
          int row = m0 + wm * 128 + mi * 16 + lk * 4 + r;
          out[(size_t)row * VV + col] = acc[mi][ni][r];
        }
      }
    }
}

extern "C" void kernel_launch(void* const* d_in, const int* in_sizes, int n_in,
                              void* d_out, int out_size, void* d_ws, size_t ws_size,
                              hipStream_t stream) {
  (void)in_sizes; (void)n_in; (void)out_size; (void)ws_size;
  const float* x     = (const float*)d_in[0];
  const float* ctx   = (const float*)d_in[1];
  const int*   lens  = (const int*)d_in[2];
  const float* Wih   = (const float*)d_in[3];
  const float* Whh   = (const float*)d_in[4];
  const float* bih   = (const float*)d_in[5];
  const float* bhh   = (const float*)d_in[6];
  const float* attWx = (const float*)d_in[7];
  const float* attWs = (const float*)d_in[8];
  const float* attb  = (const float*)d_in[9];
  const float* attv  = (const float*)d_in[10];
  const float* Wdec  = (const float*)d_in[11];
  float* out = (float*)d_out;

  char* base = (char*)d_ws;
  size_t off = 0;
  auto alloc = [&](size_t bytes) -> void* {
    off = (off + 255) & ~(size_t)255;
    void* p = base + off;
    off += bytes;
    return p;
  };
  unsigned short* ETs  = (unsigned short*)alloc((size_t)BB * SS * HH * 2);
  unsigned short* ctxb = (unsigned short*)alloc((size_t)BB * SS * HH * 2);
  float*          Xp   = (float*)alloc((size_t)BB * TT * G4 * 4);
  float*          WihxT= (float*)alloc((size_t)ID * G4 * 4);
  unsigned short* hall = (unsigned short*)alloc((size_t)BB * TT * KP * 2);
  unsigned short* Wdb  = (unsigned short*)alloc((size_t)NP2 * KP * 2);
  float*          WgT  = (float*)alloc((size_t)NJ * KK * WKP * 4);
  unsigned short* WxS  = (unsigned short*)alloc((size_t)NJ * RPB * HH * 2);
  float*          Hbuf = (float*)alloc((size_t)BB * HH * 4);
  float*          Pbuf = (float*)alloc((size_t)BB * NJ * 176 * 4);
  float*          APbuf= (float*)alloc((size_t)BB * NJ * HH * 4);
  unsigned int*   flags= (unsigned int*)alloc((size_t)2 * BB * NJ * 64 * 4);

  {
    const int TOTP = NJ * KK * WKP + NJ * RPB * HH + 2 * BB * NJ * 64 + BB * TT * (KP - HH);
    const int NBP = (TOTP + 255) / 256;
    k_prepall<<<dim3(NB_WDEC + NB_TR + NBP), dim3(256), 0, stream>>>(
        Wih, Whh, attWx, Wdec, WihxT, Wdb, WgT, WxS, flags, hall);
  }
  k_seqxp<<<dim3(1024 + 256), dim3(256), 0, stream>>>(ctx, attWs, x, WihxT,
                                                      bih, bhh, ETs, ctxb, Xp);
  {
    const int* a0 = lens; const float* a1 = attb; const float* a2 = attv;
    const float* a3 = WgT; const unsigned short* a4 = WxS;
    const unsigned short* a5 = ETs; const unsigned short* a6 = ctxb;
    const float* a7 = Xp; float* a8 = Hbuf; float* a9 = Pbuf; float* a10 = APbuf;
    unsigned int* a11 = flags; unsigned short* a12 = hall;
    void* args[] = { &a0, &a1, &a2, &a3, &a4, &a5, &a6, &a7, &a8, &a9, &a10, &a11, &a12 };
    hipLaunchCooperativeKernel((void*)k_recur, dim3(BB * NJ), dim3(512), args, 0, stream);
  }
  k_decode<<<dim3(NP2 / 256, (BB * TT) / 256), dim3(512), 0, stream>>>(hall, Wdb, out);
}

// Round 6
// 757.249 us; speedup vs baseline: 3.5149x; 1.0751x over previous
//
#include <hip/hip_runtime.h>
#include <stdint.h>

#define BB 32
#define TT 64
#define ID 300
#define HH 168
#define SS 512
#define VV 50257
#define G4 672     // 4*H
#define IC 468     // I + C
#define KP 192     // K padded for decode MFMA
#define NP2 50432  // V padded to 256 (197 tiles)
#define NJ 8       // blocks per batch (cluster size)
#define RPB 21     // h rows per block
#define CPB 84     // gate cols per block
#define KK 336     // gate K dim (attn 168 + h 168)
#define WKP 88     // WgT col pad
#define EPAD 170   // ETs LDS row pad (85 dwords, gcd(85,32)=1 -> conflict-free)
#define SBLK 64    // s positions per block
#define LP 72      // decode LDS row pad in shorts
#define LSLOT 192  // u64 slots per (b,j) bucket: a 0..167, h 168..188 / p 0..167, bsum 168

typedef float f32x4 __attribute__((ext_vector_type(4)));
typedef short bf16x8 __attribute__((ext_vector_type(8)));
typedef unsigned long long u64;

__device__ __forceinline__ float bf2f(unsigned short u) {
  union { unsigned int i; float f; } v; v.i = ((unsigned int)u) << 16; return v.f;
}
__device__ __forceinline__ unsigned short f2bf(float f) {
  union { float f; unsigned int u; } v; v.f = f;
  unsigned int r = v.u + 0x7fffu + ((v.u >> 16) & 1u);
  return (unsigned short)(r >> 16);
}
__device__ __forceinline__ float rcpf(float x) { return __builtin_amdgcn_rcpf(x); }
__device__ __forceinline__ u64 packft(float f, unsigned tag) {
  union { float f; unsigned u; } v; v.f = f;
  return ((u64)tag << 32) | (u64)v.u;
}
__device__ __forceinline__ float lo_f(u64 x) {
  union { unsigned u; float f; } v; v.u = (unsigned)x; return v.f;
}
__device__ __forceinline__ unsigned hi_u(u64 x) { return (unsigned)(x >> 32); }
__device__ __forceinline__ void postv(u64* p, u64 v) {
  __hip_atomic_store(p, v, __ATOMIC_RELAXED, __HIP_MEMORY_SCOPE_AGENT);
}
__device__ __forceinline__ u64 loadv(const u64* p) {
  return __hip_atomic_load(p, __ATOMIC_RELAXED, __HIP_MEMORY_SCOPE_AGENT);
}

// ============ prep-all: Wdb, WihxT, WgT/WxS, zero Abuf/Pbuf, hall pad ========
#define NB_WDEC 4728   // NP2*KP/8/256
#define NB_TR   788    // ceil(ID*G4/256)
__global__ void k_prepall(const float* __restrict__ Wih, const float* __restrict__ Whh,
                          const float* __restrict__ attWx, const float* __restrict__ Wd,
                          float* __restrict__ WihxT, unsigned short* __restrict__ Wdb,
                          float* __restrict__ WgT, unsigned short* __restrict__ WxS,
                          u64* __restrict__ Abuf, u64* __restrict__ Pbuf,
                          unsigned short* __restrict__ hall) {
  const int bid = blockIdx.x, tid = threadIdx.x;
  if (bid < NB_WDEC) {
    size_t e0 = ((size_t)bid * 256 + tid) * 8;
    int v = (int)(e0 / KP), k = (int)(e0 - (size_t)v * KP);
    unsigned short o[8];
    if (v < VV && k < HH) {
      const float* src = Wd + (size_t)v * HH + k;
      #pragma unroll
      for (int i = 0; i < 8; ++i) o[i] = f2bf(src[i]);
    } else {
      #pragma unroll
      for (int i = 0; i < 8; ++i) o[i] = 0;
    }
    *(uint4*)(Wdb + e0) = *(const uint4*)o;
    return;
  }
  if (bid < NB_WDEC + NB_TR) {
    int idx = (bid - NB_WDEC) * 256 + tid;
    if (idx < ID * G4) {
      int k = idx / G4, i = idx - k * G4;
      WihxT[idx] = Wih[(size_t)i * IC + k];
    }
    return;
  }
  int idx = (bid - NB_WDEC - NB_TR) * 256 + tid;
  const int T1 = NJ * KK * WKP;             // 236544
  const int T2 = T1 + NJ * RPB * HH;        // +28224
  const int ZH = BB * NJ * LSLOT;           // 49152 u64 per buffer
  const int T3 = T2 + 2 * ZH;               // zero Abuf+Pbuf
  const int T4 = T3 + BB * TT * (KP - HH);  // hall pad
  if (idx < T1) {
    int j = idx / (KK * WKP); int r = idx - j * (KK * WKP);
    int k = r / WKP, col = r - k * WKP;
    float w = 0.f;
    if (col < CPB) {
      int gt = col / RPB, rr = col - gt * RPB;
      int gcol = gt * HH + j * RPB + rr;
      w = (k < HH) ? Wih[(size_t)gcol * IC + ID + k] : Whh[(size_t)gcol * HH + (k - HH)];
    }
    WgT[idx] = w;
  } else if (idx < T2) {
    int r = idx - T1;
    WxS[r] = f2bf(attWx[r]);
  } else if (idx < T3) {
    int r = idx - T2;
    if (r < ZH) Abuf[r] = 0ull;
    else        Pbuf[r - ZH] = 0ull;
  } else if (idx < T4) {
    int r = idx - T3;
    int bt = r / (KP - HH), c = r - bt * (KP - HH);
    hall[(size_t)bt * KP + HH + c] = 0;
  }
}

// ============ seqproj (blocks 0..1023) + xproj (blocks 1024..1279) ===========
__global__ void k_seqxp(const float* __restrict__ ctx, const float* __restrict__ Ws,
                        const float* __restrict__ x, const float* __restrict__ WihxT,
                        const float* __restrict__ bih, const float* __restrict__ bhh,
                        unsigned short* __restrict__ ETs, unsigned short* __restrict__ ctxb,
                        float* __restrict__ Xp) {
  __shared__ float sbuf[2688];
  const int tid = threadIdx.x;
  if (blockIdx.x < 1024) {
    const int b = blockIdx.x & 31;
    const int s0 = (blockIdx.x >> 5) * 16;
    for (int idx = tid; idx < 16 * HH; idx += 256) {
      float v = ctx[(size_t)(b * SS + s0) * HH + idx];
      sbuf[idx] = v;
      ctxb[(size_t)(b * SS + s0) * HH + idx] = f2bf(v);
    }
    __syncthreads();
    #pragma unroll
    for (int o = 0; o < 11; ++o) {
      int idx = o * 256 + tid;
      if (idx < 16 * HH) {
        int s = idx / HH, h = idx - s * HH;
        const float* cr = &sbuf[s * HH];
        float acc = 0.f;
        #pragma unroll 4
        for (int c = 0; c < HH; ++c) acc = fmaf(cr[c], Ws[c * HH + h], acc);
        ETs[(size_t)(b * SS + s0 + s) * HH + h] = f2bf(__expf(2.f * acc));
      }
    }
  } else {
    const int r = blockIdx.x - 1024;
    const int t0 = (r & 7) * 8;
    const int b = r >> 3;
    for (int idx = tid; idx < 8 * ID; idx += 256)
      sbuf[idx] = x[(size_t)(b * TT + t0) * ID + idx];
    __syncthreads();
    for (int i = tid; i < G4; i += 256) {
      float bias = bih[i] + bhh[i];
      float acc[8];
      #pragma unroll
      for (int tt = 0; tt < 8; ++tt) acc[tt] = bias;
      for (int k = 0; k < ID; ++k) {
        float w = WihxT[k * G4 + i];
        #pragma unroll
        for (int tt = 0; tt < 8; ++tt) acc[tt] += sbuf[tt * ID + k] * w;
      }
      #pragma unroll
      for (int tt = 0; tt < 8; ++tt)
        Xp[(size_t)(b * TT + t0 + tt) * G4 + i] = acc[tt];
    }
  }
}

// ============ recurrence: 8 blocks/batch, tag-embedded sync, 7 barriers ======
__global__ __launch_bounds__(512, 1) void k_recur(
    const int* __restrict__ lens, const float* __restrict__ attb,
    const float* __restrict__ attv, const float* __restrict__ WgT,
    const unsigned short* __restrict__ WxS, const unsigned short* __restrict__ ETs,
    const unsigned short* __restrict__ ctxb, const float* __restrict__ Xp,
    u64* __restrict__ Abuf, u64* __restrict__ Pbuf,
    unsigned short* __restrict__ hall) {
  const int b = blockIdx.x & 31;
  const int j = blockIdx.x >> 5;
  const int tid = threadIdx.x;

  __shared__ float WgL[KK][WKP];            // 118272 B, [k][col]
  __shared__ unsigned short EL[SBLK][EPAD]; // 21760 B
  __shared__ unsigned short WxL[RPB][HH];   // 7056 B
  __shared__ float scratch[512];
  __shared__ float redH[504], redC[504];
  __shared__ float gE[HH], hsh[HH], abL[HH], vL[HH], attn[HH];
  __shared__ float esh[SBLK], hLoc[RPB], cLoc[RPB], wsum[8];
  __shared__ float sumv_s, bsum_s;

  {
    const f32x4* src = (const f32x4*)(WgT + (size_t)j * KK * WKP);
    f32x4* dst = (f32x4*)WgL;
    for (int i = tid; i < KK * WKP / 4; i += 512) dst[i] = src[i];
  }
  for (int i = tid; i < SBLK * HH; i += 512) {
    int s = i / HH, h = i - s * HH;
    EL[s][h] = ETs[((size_t)b * SS + j * SBLK + s) * HH + h];
  }
  for (int i = tid; i < RPB * HH; i += 512)
    ((unsigned short*)WxL)[i] = WxS[(size_t)j * RPB * HH + i];
  if (tid < HH) { abL[tid] = attb[tid]; vL[tid] = attv[tid]; }
  if (tid < RPB) cLoc[tid] = 0.f;
  __syncthreads();
  if (tid == 0) {
    float s = 0.f;
    for (int h = 0; h < HH; ++h) s += vL[h];
    sumv_s = s;
  }
  const int len = lens[b];
  const int sbase = j * SBLK;
  u64* Amine = Abuf + (size_t)(b * NJ + j) * LSLOT;
  u64* Pmine = Pbuf + (size_t)(b * NJ + j) * LSLOT;
  __syncthreads();

  for (int t = 0; t < TT; ++t) {
    // prefetch Xp gates for this block's 21 rows (consumed late)
    float xpr0 = 0.f, xpr1 = 0.f, xpr2 = 0.f, xpr3 = 0.f;
    if (tid < RPB) {
      const float* xp = Xp + ((size_t)b * TT + t) * G4 + j * RPB + tid;
      xpr0 = xp[0]; xpr1 = xp[HH]; xpr2 = xp[2 * HH]; xpr3 = xp[3 * HH];
    }
    // ---- gE + hsh: poll tag-embedded a-partials (8) + h value (1)
    if (tid < HH) {
      float a = abL[tid], hv = 0.f;
      if (t > 0) {
        const unsigned want = (unsigned)t;
        const int jh = tid / RPB, hr = tid - jh * RPB;
        u64 va[9];
        int g = 0;
        for (;;) {
          #pragma unroll
          for (int jj = 0; jj < NJ; ++jj)
            va[jj] = loadv(&Abuf[(size_t)(b * NJ + jj) * LSLOT + tid]);
          va[8] = loadv(&Abuf[(size_t)(b * NJ + jh) * LSLOT + HH + hr]);
          bool ok = true;
          #pragma unroll
          for (int q = 0; q < 9; ++q) ok &= (hi_u(va[q]) >= want);
          if (ok) break;
          __builtin_amdgcn_s_sleep(1);
          if (++g > (1 << 24)) break;
        }
        #pragma unroll
        for (int jj = 0; jj < NJ; ++jj) a += lo_f(va[jj]);
        hv = lo_f(va[8]);
      }
      gE[tid] = __expf(2.f * a);
      hsh[tid] = hv;
    }
    __syncthreads();                                     // BAR A
    // ---- B + softmax (wave-local)
    {
      int w = tid >> 6, lane = tid & 63;
      int sl = w * 8 + (lane >> 3);
      int hg = lane & 7;
      const unsigned short* er = &EL[sl][hg * RPB];
      const int hb = hg * RPB;
      float ep = 0.f;
      #pragma unroll 7
      for (int i = 0; i < RPB; ++i)
        ep += vL[hb + i] * rcpf(fmaf(gE[hb + i], bf2f(er[i]), 1.f));
      ep += __shfl_xor(ep, 1); ep += __shfl_xor(ep, 2); ep += __shfl_xor(ep, 4);
      float eh = (sbase + sl < len) ? __expf(sumv_s - 2.f * ep) : 0.f;
      float ws = (hg == 0) ? eh : 0.f;
      ws += __shfl_xor(ws, 8); ws += __shfl_xor(ws, 16); ws += __shfl_xor(ws, 32);
      if (lane == 0) wsum[w] = ws;
      if (hg == 0) esh[sl] = eh;
    }
    __syncthreads();                                     // BAR B
    // ---- C partials + bsum
    if (tid < 504) {
      int c = tid % HH, ch = tid / HH;
      const unsigned short* cb = ctxb + ((size_t)b * SS + sbase) * HH + c;
      float p = 0.f;
      for (int s = ch; s < SBLK; s += 3)
        p = fmaf(esh[s], bf2f(cb[(size_t)s * HH]), p);
      scratch[ch * HH + c] = p;
    } else if (tid == 504) {
      float bs = 0.f;
      #pragma unroll
      for (int w = 0; w < 8; ++w) bs += wsum[w];
      bsum_s = bs;
    }
    __syncthreads();                                     // BAR C
    // ---- post P (tag-embedded; no drain, no flag)
    if (tid < HH) {
      float p = scratch[tid] + scratch[HH + tid] + scratch[2 * HH + tid];
      postv(&Pmine[tid], packft(p, (unsigned)(t + 1)));
    } else if (tid == HH) {
      postv(&Pmine[HH], packft(bsum_s, (unsigned)(t + 1)));
    }
    // ---- D_h (overlaps P propagation)
    if (tid < 504) {
      int col = tid % CPB, kc = tid / CPB;
      int k0 = HH + kc * 28;
      float acc = 0.f;
      #pragma unroll 7
      for (int i = 0; i < 28; ++i)
        acc = fmaf(WgL[k0 + i][col], hsh[kc * 28 + i], acc);
      redH[kc * CPB + col] = acc;
    }
    // ---- attn finalize: poll 8 p-lines + 8 bsum lines directly
    if (tid < HH) {
      const unsigned want = (unsigned)(t + 1);
      u64 pv[NJ], bv[NJ];
      int g = 0;
      for (;;) {
        #pragma unroll
        for (int jj = 0; jj < NJ; ++jj) {
          const u64* pb = Pbuf + (size_t)(b * NJ + jj) * LSLOT;
          pv[jj] = loadv(&pb[tid]);
          bv[jj] = loadv(&pb[HH]);
        }
        bool ok = true;
        #pragma unroll
        for (int jj = 0; jj < NJ; ++jj) ok &= (hi_u(pv[jj]) >= want) & (hi_u(bv[jj]) >= want);
        if (ok) break;
        __builtin_amdgcn_s_sleep(1);
        if (++g > (1 << 24)) break;
      }
      float s = 0.f, den = 0.f;
      #pragma unroll
      for (int jj = 0; jj < NJ; ++jj) { s += lo_f(pv[jj]); den += lo_f(bv[jj]); }
      attn[tid] = s * rcpf(den);
    }
    __syncthreads();                                     // BAR D
    // ---- D_c
    if (tid < 504) {
      int col = tid % CPB, kc = tid / CPB;
      int k0 = kc * 28;
      float acc = 0.f;
      #pragma unroll 7
      for (int i = 0; i < 28; ++i)
        acc = fmaf(WgL[k0 + i][col], attn[k0 + i], acc);
      redC[kc * CPB + col] = acc;
    }
    __syncthreads();                                     // BAR E
    // ---- gates + LSTM (21 threads)
    if (tid < RPB) {
      float g0 = xpr0, g1 = xpr1, g2 = xpr2, g3 = xpr3;
      #pragma unroll
      for (int kc = 0; kc < 6; ++kc) {
        const float* rh = &redH[kc * CPB];
        const float* rc = &redC[kc * CPB];
        g0 += rh[tid] + rc[tid];
        g1 += rh[RPB + tid] + rc[RPB + tid];
        g2 += rh[2 * RPB + tid] + rc[2 * RPB + tid];
        g3 += rh[3 * RPB + tid] + rc[3 * RPB + tid];
      }
      float si = rcpf(1.f + __expf(-g0));
      float sf = rcpf(1.f + __expf(-g1));
      float tg = 1.f - 2.f * rcpf(1.f + __expf(2.f * g2));
      float so = rcpf(1.f + __expf(-g3));
      float cn = fmaf(sf, cLoc[tid], si * tg);
      float tc = 1.f - 2.f * rcpf(1.f + __expf(2.f * cn));
      float hn = so * tc;
      cLoc[tid] = cn; hLoc[tid] = hn;
      hall[((size_t)b * TT + t) * KP + j * RPB + tid] = f2bf(hn);
    }
    __syncthreads();                                     // BAR F
    // ---- a_j = h_slice @ Wx_slice
    if (tid < 504) {
      int col = tid % HH, ch = tid / HH;
      float acc = 0.f;
      #pragma unroll
      for (int r = ch * 7; r < ch * 7 + 7; ++r)
        acc = fmaf(hLoc[r], bf2f(WxL[r][col]), acc);
      scratch[ch * HH + col] = acc;
    }
    __syncthreads();                                     // BAR G
    // ---- post a-partials + h values (tag-embedded)
    if (tid < HH) {
      float a = scratch[tid] + scratch[HH + tid] + scratch[2 * HH + tid];
      postv(&Amine[tid], packft(a, (unsigned)(t + 1)));
    } else if (tid < HH + RPB) {
      postv(&Amine[tid], packft(hLoc[tid - HH], (unsigned)(t + 1)));
    }
  }
}

// ============ decode GEMM: 256x256 tiles, 512 threads ========================
__global__ __launch_bounds__(512, 1) void k_decode(const unsigned short* __restrict__ hallb,
                                                   const unsigned short* __restrict__ wdb,
                                                   float* __restrict__ out) {
  __shared__ __align__(16) unsigned short As[256 * LP];
  __shared__ __align__(16) unsigned short Bs[256 * LP];
  const int tid = threadIdx.x;
  const int n0 = blockIdx.x * 256, m0 = blockIdx.y * 256;
  const int lane = tid & 63, wid = tid >> 6;
  const int wm = wid >> 2, wn = wid & 3;
  const int lr = lane & 15, lk = lane >> 4;
  f32x4 acc[8][4];
  #pragma unroll
  for (int i = 0; i < 8; ++i)
    #pragma unroll
    for (int jj = 0; jj < 4; ++jj) acc[i][jj] = (f32x4)0.f;

  for (int k0 = 0; k0 < KP; k0 += 64) {
    if (k0) __syncthreads();
    #pragma unroll
    for (int i = 0; i < 4; ++i) {
      int flat = i * 512 + tid;
      int row = flat >> 3;
      int c8 = flat & 7;
      uint4 va = *(const uint4*)(hallb + (size_t)(m0 + row) * KP + k0 + c8 * 8);
      *(uint4*)&As[row * LP + c8 * 8] = va;
      uint4 vb = *(const uint4*)(wdb + (size_t)(n0 + row) * KP + k0 + c8 * 8);
      *(uint4*)&Bs[row * LP + c8 * 8] = vb;
    }
    __syncthreads();
    #pragma unroll
    for (int kk = 0; kk < 64; kk += 32) {
      bf16x8 af[8], bfr[4];
      #pragma unroll
      for (int mi = 0; mi < 8; ++mi)
        af[mi] = *(const bf16x8*)&As[(wm * 128 + mi * 16 + lr) * LP + kk + lk * 8];
      #pragma unroll
      for (int ni = 0; ni < 4; ++ni)
        bfr[ni] = *(const bf16x8*)&Bs[(wn * 64 + ni * 16 + lr) * LP + kk + lk * 8];
      #pragma unroll
      for (int mi = 0; mi < 8; ++mi)
        #pragma unroll
        for (int ni = 0; ni < 4; ++ni)
          acc[mi][ni] = __builtin_amdgcn_mfma_f32_16x16x32_bf16(
              af[mi], bfr[ni], acc[mi][ni], 0, 0, 0);
    }
  }
  #pragma unroll
  for (int mi = 0; mi < 8; ++mi)
    #pragma unroll
    for (int ni = 0; ni < 4; ++ni) {
      int col = n0 + wn * 64 + ni * 16 + lr;
      if (col < VV) {
        #pragma unroll
        for (int r = 0; r < 4; ++r) {
          int row = m0 + wm * 128 + mi * 16 + lk * 4 + r;
          out[(size_t)row * VV + col] = acc[mi][ni][r];
        }
      }
    }
}

extern "C" void kernel_launch(void* const* d_in, const int* in_sizes, int n_in,
                              void* d_out, int out_size, void* d_ws, size_t ws_size,
                              hipStream_t stream) {
  (void)in_sizes; (void)n_in; (void)out_size; (void)ws_size;
  const float* x     = (const float*)d_in[0];
  const float* ctx   = (const float*)d_in[1];
  const int*   lens  = (const int*)d_in[2];
  const float* Wih   = (const float*)d_in[3];
  const float* Whh   = (const float*)d_in[4];
  const float* bih   = (const float*)d_in[5];
  const float* bhh   = (const float*)d_in[6];
  const float* attWx = (const float*)d_in[7];
  const float* attWs = (const float*)d_in[8];
  const float* attb  = (const float*)d_in[9];
  const float* attv  = (const float*)d_in[10];
  const float* Wdec  = (const float*)d_in[11];
  float* out = (float*)d_out;

  char* base = (char*)d_ws;
  size_t off = 0;
  auto alloc = [&](size_t bytes) -> void* {
    off = (off + 255) & ~(size_t)255;
    void* p = base + off;
    off += bytes;
    return p;
  };
  unsigned short* ETs  = (unsigned short*)alloc((size_t)BB * SS * HH * 2);
  unsigned short* ctxb = (unsigned short*)alloc((size_t)BB * SS * HH * 2);
  float*          Xp   = (float*)alloc((size_t)BB * TT * G4 * 4);
  float*          WihxT= (float*)alloc((size_t)ID * G4 * 4);
  unsigned short* hall = (unsigned short*)alloc((size_t)BB * TT * KP * 2);
  unsigned short* Wdb  = (unsigned short*)alloc((size_t)NP2 * KP * 2);
  float*          WgT  = (float*)alloc((size_t)NJ * KK * WKP * 4);
  unsigned short* WxS  = (unsigned short*)alloc((size_t)NJ * RPB * HH * 2);
  u64*            Abuf = (u64*)alloc((size_t)BB * NJ * LSLOT * 8);
  u64*            Pbuf = (u64*)alloc((size_t)BB * NJ * LSLOT * 8);

  {
    const int TOTP = NJ * KK * WKP + NJ * RPB * HH + 2 * BB * NJ * LSLOT + BB * TT * (KP - HH);
    const int NBP = (TOTP + 255) / 256;
    k_prepall<<<dim3(NB_WDEC + NB_TR + NBP), dim3(256), 0, stream>>>(
        Wih, Whh, attWx, Wdec, WihxT, Wdb, WgT, WxS, Abuf, Pbuf, hall);
  }
  k_seqxp<<<dim3(1024 + 256), dim3(256), 0, stream>>>(ctx, attWs, x, WihxT,
                                                      bih, bhh, ETs, ctxb, Xp);
  {
    const int* a0 = lens; const float* a1 = attb; const float* a2 = attv;
    const float* a3 = WgT; const unsigned short* a4 = WxS;
    const unsigned short* a5 = ETs; const unsigned short* a6 = ctxb;
    const float* a7 = Xp; u64* a8 = Abuf; u64* a9 = Pbuf;
    unsigned short* a10 = hall;
    void* args[] = { &a0, &a1, &a2, &a3, &a4, &a5, &a6, &a7, &a8, &a9, &a10 };
    hipLaunchCooperativeKernel((void*)k_recur, dim3(BB * NJ), dim3(512), args, 0, stream);
  }
  k_decode<<<dim3(NP2 / 256, (BB * TT) / 256), dim3(512), 0, stream>>>(hall, Wdb, out);
}